// Round 10
// baseline (13911.798 us; speedup 1.0000x reference)
//
#include <hip/hip_runtime.h>
#include <cstdint>
#include <cstddef>

#define SEQ   2048
#define BATCH 64
#define HID   512

// ---------------------------------------------------------------------------
// proj GEMM: C[m][n] = sum_k A[m][k] * W[n][k] + bias[n]
// ---------------------------------------------------------------------------
__global__ __launch_bounds__(256)
void proj_gemm(const float* __restrict__ A, const float* __restrict__ W,
               const float* __restrict__ bias, float* __restrict__ C)
{
    __shared__ float As[16][132];
    __shared__ float Bs[16][132];
    const int t  = threadIdx.x;
    const int bm = blockIdx.x >> 2;
    const int bn = blockIdx.x & 3;
    const int m0 = bm * 128;
    const int n0 = bn * 128;
    const int tn = t & 15;
    const int tm = t >> 4;

    float acc[8][8];
#pragma unroll
    for (int i = 0; i < 8; ++i)
#pragma unroll
        for (int j = 0; j < 8; ++j) acc[i][j] = 0.f;

    const int lrow = t >> 2;
    const int lk4  = t & 3;

    for (int kk = 0; kk < 512; kk += 16) {
#pragma unroll
        for (int i = 0; i < 2; ++i) {
            const int row = lrow + i * 64;
            float4 va = *(const float4*)&A[(size_t)(m0 + row) * 512 + kk + lk4 * 4];
            As[lk4 * 4 + 0][row] = va.x;
            As[lk4 * 4 + 1][row] = va.y;
            As[lk4 * 4 + 2][row] = va.z;
            As[lk4 * 4 + 3][row] = va.w;
            float4 vb = *(const float4*)&W[(size_t)(n0 + row) * 512 + kk + lk4 * 4];
            Bs[lk4 * 4 + 0][row] = vb.x;
            Bs[lk4 * 4 + 1][row] = vb.y;
            Bs[lk4 * 4 + 2][row] = vb.z;
            Bs[lk4 * 4 + 3][row] = vb.w;
        }
        __syncthreads();
#pragma unroll
        for (int k = 0; k < 16; ++k) {
            float4 a0 = *(const float4*)&As[k][tm * 8];
            float4 a1 = *(const float4*)&As[k][tm * 8 + 4];
            float4 b0 = *(const float4*)&Bs[k][tn * 4];
            float4 b1 = *(const float4*)&Bs[k][64 + tn * 4];
            float ar[8] = {a0.x, a0.y, a0.z, a0.w, a1.x, a1.y, a1.z, a1.w};
            float bc[8] = {b0.x, b0.y, b0.z, b0.w, b1.x, b1.y, b1.z, b1.w};
#pragma unroll
            for (int i = 0; i < 8; ++i)
#pragma unroll
                for (int j = 0; j < 8; ++j)
                    acc[i][j] = fmaf(ar[i], bc[j], acc[i][j]);
        }
        __syncthreads();
    }

    float4 bv0 = *(const float4*)&bias[n0 + tn * 4];
    float4 bv1 = *(const float4*)&bias[n0 + 64 + tn * 4];
    const float bb[8] = {bv0.x, bv0.y, bv0.z, bv0.w, bv1.x, bv1.y, bv1.z, bv1.w};
#pragma unroll
    for (int i = 0; i < 8; ++i) {
        const size_t rowoff = (size_t)(m0 + tm * 8 + i) * 512 + n0;
        float4 o0, o1;
        o0.x = acc[i][0] + bb[0]; o0.y = acc[i][1] + bb[1];
        o0.z = acc[i][2] + bb[2]; o0.w = acc[i][3] + bb[3];
        o1.x = acc[i][4] + bb[4]; o1.y = acc[i][5] + bb[5];
        o1.z = acc[i][6] + bb[6]; o1.w = acc[i][7] + bb[7];
        *(float4*)&C[rowoff + tn * 4] = o0;
        *(float4*)&C[rowoff + 64 + tn * 4] = o1;
    }
}

// fast tanh: 1 - 2/(exp2(2*log2e*x)+1); exact at +/-inf, ~1e-6 abs error
__device__ __forceinline__ float fast_tanh(float x)
{
    const float e = __builtin_amdgcn_exp2f(x * 2.88539008177793f);
    return fmaf(-2.0f, __builtin_amdgcn_rcpf(e + 1.0f), 1.0f);
}

// ---------------------------------------------------------------------------
// Recurrent scan with BATCH ROTATION to hide sync RT.
// 256 WGs x 512 thr, 1 WG/CU (84 KB LDS). Group g (16 groups) = 4 batch
// elems (4g..4g+3) as 2 pairs; 16 slice-WGs per group (bid = g + 16s -> all
// on XCD g%8). Slice owns rows [32s, 32s+32); W slice (32x512 f32 = 64 KB)
// in LDS, layout WL[j][t] -> per j a wave reads 64 consecutive float4s.
//
// Phase k (2 per step): compute pair P=k&1 at step S=k>>1.
//  1. issue relaxed agent-scope poll loads for the NEXT phase's pair
//     (published one phase ago -> RT overlaps this phase's compute)
//  2. matvec pair P from LDS (W reused for both elems), 4x shfl_xor reduce
//  3. publish tagged u64 {S+1, h} (relaxed agent atomics, parity dbuf),
//     self-route own rows into LDS
//  4. check poll tags (spin only if not yet landed), stage into LDS
//  5. ONE barrier
// hbuf parity reuse gap = 4 phases => overwrite race closed under skew
// (a WG publishing step S+3 proves all WGs completed step S+1 polls).
// h LDS buffers 9-float4 strided => broadcast reads <=2-way bank alias.
// ---------------------------------------------------------------------------
__global__ __launch_bounds__(512, 2)
void rnn_scan(const float* __restrict__ proj, const float* __restrict__ Whh,
              const float* __restrict__ bhh, float* __restrict__ out,
              float* __restrict__ hidden, unsigned long long* __restrict__ hbuf)
{
    extern __shared__ float lds[];
    float4* WL  = (float4*)lds;              // [8][512] float4 = 64 KB
    float4* hL4 = (float4*)(lds + 16384);    // [P][par][e][144] float4
    float*  hLf = lds + 16384;               // scalar view (4608 floats)

    const int t    = threadIdx.x;
    const int bid  = blockIdx.x;
    const int g    = bid & 15;               // group
    const int s    = bid >> 4;               // slice 0..15 (same XCD per group)
    const int base = s * 32;
    const int rl   = t >> 4;                 // row-in-slice 0..31
    const int kc   = t & 15;                 // k-chunk 0..15 (32 k each)
    const int row  = base + rl;
    const int e00  = g * 4;                  // group's first batch elem

    // ---- one-time: W slice -> LDS, wave-block layout ----
    const float4* W4 = (const float4*)Whh;
#pragma unroll
    for (int j = 0; j < 8; ++j)
        WL[j * 512 + t] = W4[(size_t)row * 128 + kc * 8 + j];

    const bool pub  = (kc < 2);
    const float breg = pub ? bhh[row] : 0.f;

    for (int i = t; i < 4608; i += 512) hLf[i] = 0.f;
    __syncthreads();

    const bool own = (t >= base) && (t < base + 32);
    unsigned long long* gb = hbuf + (size_t)g * 4096;  // [P][par][e][512]

    float pv0 = 0.f, pv1 = 0.f;
    if (pub) {
        pv0 = proj[(size_t)(e00 + 0 + kc) * HID + row];   // pair0, step 0
        pv1 = proj[(size_t)(e00 + 2 + kc) * HID + row];   // pair1, step 0
    }

    auto phase = [&](const int P, const int S, float& pv) {
        const int Pn = P ^ 1;
        const int Sn = S + P;              // P=0 -> poll (1,S); P=1 -> (0,S+1)
        const int pr = S & 1;
        const bool dopoll = (!own) && (Sn < SEQ);

        // ---- 1. issue poll loads early (RT hides under compute) ----
        unsigned long long x0 = 0, x1 = 0;
        unsigned long long* pb = gb + (size_t)Pn * 2048 + (size_t)(Sn & 1) * 1024;
        if (dopoll) {
            x0 = __hip_atomic_load(pb + t,       __ATOMIC_RELAXED, __HIP_MEMORY_SCOPE_AGENT);
            x1 = __hip_atomic_load(pb + 512 + t, __ATOMIC_RELAXED, __HIP_MEMORY_SCOPE_AGENT);
        }

        // ---- 2. matvec: W (shared across pair) x h from LDS ----
        const float4* ha = hL4 + ((size_t)(P * 2 + pr) * 2 + 0) * 144 + kc * 9;
        const float4* hb = ha + 144;
        const float4* wb = WL + t;
        float A0 = 0.f, B0 = 0.f, A1 = 0.f, B1 = 0.f;
#pragma unroll
        for (int j = 0; j < 8; j += 2) {
            float4 w0 = wb[j * 512];
            float4 w1 = wb[(j + 1) * 512];
            float4 p0 = ha[j], p1 = ha[j + 1];
            float4 q0 = hb[j], q1 = hb[j + 1];
            A0 = fmaf(w0.x, p0.x, A0); A0 = fmaf(w0.y, p0.y, A0);
            A0 = fmaf(w0.z, p0.z, A0); A0 = fmaf(w0.w, p0.w, A0);
            B0 = fmaf(w0.x, q0.x, B0); B0 = fmaf(w0.y, q0.y, B0);
            B0 = fmaf(w0.z, q0.z, B0); B0 = fmaf(w0.w, q0.w, B0);
            A1 = fmaf(w1.x, p1.x, A1); A1 = fmaf(w1.y, p1.y, A1);
            A1 = fmaf(w1.z, p1.z, A1); A1 = fmaf(w1.w, p1.w, A1);
            B1 = fmaf(w1.x, q1.x, B1); B1 = fmaf(w1.y, q1.y, B1);
            B1 = fmaf(w1.z, q1.z, B1); B1 = fmaf(w1.w, q1.w, B1);
        }
        float t0 = A0 + A1, t1 = B0 + B1;
        t0 += __shfl_xor(t0, 1, 64); t1 += __shfl_xor(t1, 1, 64);
        t0 += __shfl_xor(t0, 2, 64); t1 += __shfl_xor(t1, 2, 64);
        t0 += __shfl_xor(t0, 4, 64); t1 += __shfl_xor(t1, 4, 64);
        t0 += __shfl_xor(t0, 8, 64); t1 += __shfl_xor(t1, 8, 64);

        // ---- 3. publish ASAP (critical path for other WGs) ----
        if (pub) {
            const int elem = e00 + P * 2 + kc;
            const float sum = (kc == 0) ? t0 : t1;
            const float hn = fast_tanh(pv + breg + sum);
            out[((size_t)S * BATCH + elem) * HID + row] = hn;
            const unsigned long long pk =
                ((unsigned long long)(unsigned)(S + 1) << 32) |
                (unsigned long long)__float_as_uint(hn);
            __hip_atomic_store(gb + (size_t)P * 2048 + (size_t)((S + 1) & 1) * 1024
                               + (size_t)kc * 512 + row,
                               pk, __ATOMIC_RELAXED, __HIP_MEMORY_SCOPE_AGENT);
            hLf[((size_t)(P * 2 + ((S + 1) & 1)) * 2 + kc) * 576
                + (row >> 5) * 36 + (row & 31)] = hn;      // self-route
            if (S == SEQ - 1) hidden[(size_t)elem * HID + row] = hn;
            if (S + 1 < SEQ)
                pv = proj[((size_t)(S + 1) * BATCH + elem) * HID + row];
        }

        // ---- 4. check tags, stage into LDS ----
        if (dopoll) {
            const unsigned want = (unsigned)Sn;
            int spins = 0;
            while (((unsigned)(x0 >> 32) != want) | ((unsigned)(x1 >> 32) != want)) {
                __builtin_amdgcn_s_sleep(1);
                if ((unsigned)(x0 >> 32) != want)
                    x0 = __hip_atomic_load(pb + t, __ATOMIC_RELAXED, __HIP_MEMORY_SCOPE_AGENT);
                if ((unsigned)(x1 >> 32) != want)
                    x1 = __hip_atomic_load(pb + 512 + t, __ATOMIC_RELAXED, __HIP_MEMORY_SCOPE_AGENT);
                if (++spins > 4096) {               // hang-proofing only
                    __builtin_amdgcn_fence(__ATOMIC_ACQUIRE, "agent");
                    spins = 0;
                }
            }
            const int hfb = ((Pn * 2 + (Sn & 1)) * 2) * 576 + (t >> 5) * 36 + (t & 31);
            hLf[hfb]       = __uint_as_float((unsigned)x0);
            hLf[hfb + 576] = __uint_as_float((unsigned)x1);
        }
        __syncthreads();   // the ONLY barrier per phase
    };

    for (int S = 0; S < SEQ; ++S) {
        phase(0, S, pv0);
        phase(1, S, pv1);
    }
}

// ---------------------------------------------------------------------------
extern "C" void kernel_launch(void* const* d_in, const int* in_sizes, int n_in,
                              void* d_out, int out_size, void* d_ws, size_t ws_size,
                              hipStream_t stream)
{
    (void)in_sizes; (void)n_in; (void)out_size; (void)ws_size;

    const float* x    = (const float*)d_in[0];
    const float* Wih0 = (const float*)d_in[1];
    const float* Whh0 = (const float*)d_in[2];
    const float* bih0 = (const float*)d_in[3];
    const float* bhh0 = (const float*)d_in[4];
    const float* Wih1 = (const float*)d_in[5];
    const float* Whh1 = (const float*)d_in[6];
    const float* bih1 = (const float*)d_in[7];
    const float* bhh1 = (const float*)d_in[8];

    float* out1   = (float*)d_out;                        // [S][B][H]
    float* hidden = out1 + (size_t)SEQ * BATCH * HID;     // [2][B][H]

    float* proj = (float*)d_ws;                           // [S][B][H] f32
    // per-layer tagged h buffers: [16 groups][2 pair][2 parity][2 e][512] u64
    unsigned long long* hbufA = (unsigned long long*)(proj + (size_t)SEQ * BATCH * HID);
    unsigned long long* hbufB = hbufA + (size_t)16 * 4096;

    // zero both layers' tag arrays (tag 0 == epoch 0, h = 0)
    hipMemsetAsync(hbufA, 0, (size_t)2 * 16 * 4096 * sizeof(unsigned long long),
                   stream);

    const size_t shmem = (size_t)(16384 + 4608) * sizeof(float);  // 83968 B
    (void)hipFuncSetAttribute((const void*)rnn_scan,
                              hipFuncAttributeMaxDynamicSharedMemorySize, (int)shmem);

    // ---- layer 0 ----
    proj_gemm<<<dim3(4096), dim3(256), 0, stream>>>(x, Wih0, bih0, proj);
    {
        const float* p = proj; const float* w = Whh0; const float* bb = bhh0;
        float* o = out1; float* hd = hidden; unsigned long long* hb = hbufA;
        void* args[] = {&p, &w, &bb, &o, &hd, &hb};
        hipLaunchCooperativeKernel((const void*)rnn_scan, dim3(256), dim3(512),
                                   args, (unsigned)shmem, stream);
    }

    // ---- layer 1 (out0 staged in d_out's out1 region) ----
    proj_gemm<<<dim3(4096), dim3(256), 0, stream>>>(out1, Wih1, bih1, proj);
    {
        const float* p = proj; const float* w = Whh1; const float* bb = bhh1;
        float* o = out1; float* hd = hidden + BATCH * HID; unsigned long long* hb = hbufB;
        void* args[] = {&p, &w, &bb, &o, &hd, &hb};
        hipLaunchCooperativeKernel((const void*)rnn_scan, dim3(256), dim3(512),
                                   args, (unsigned)shmem, stream);
    }
}

// Round 11
// 9570.245 us; speedup vs baseline: 1.4537x; 1.4537x over previous
//
#include <hip/hip_runtime.h>
#include <cstdint>
#include <cstddef>

#define SEQ   2048
#define BATCH 64
#define HID   512

// ---------------------------------------------------------------------------
// proj GEMM: C[m][n] = sum_k A[m][k] * W[n][k] + bias[n]
// ---------------------------------------------------------------------------
__global__ __launch_bounds__(256)
void proj_gemm(const float* __restrict__ A, const float* __restrict__ W,
               const float* __restrict__ bias, float* __restrict__ C)
{
    __shared__ float As[16][132];
    __shared__ float Bs[16][132];
    const int t  = threadIdx.x;
    const int bm = blockIdx.x >> 2;
    const int bn = blockIdx.x & 3;
    const int m0 = bm * 128;
    const int n0 = bn * 128;
    const int tn = t & 15;
    const int tm = t >> 4;

    float acc[8][8];
#pragma unroll
    for (int i = 0; i < 8; ++i)
#pragma unroll
        for (int j = 0; j < 8; ++j) acc[i][j] = 0.f;

    const int lrow = t >> 2;
    const int lk4  = t & 3;

    for (int kk = 0; kk < 512; kk += 16) {
#pragma unroll
        for (int i = 0; i < 2; ++i) {
            const int row = lrow + i * 64;
            float4 va = *(const float4*)&A[(size_t)(m0 + row) * 512 + kk + lk4 * 4];
            As[lk4 * 4 + 0][row] = va.x;
            As[lk4 * 4 + 1][row] = va.y;
            As[lk4 * 4 + 2][row] = va.z;
            As[lk4 * 4 + 3][row] = va.w;
            float4 vb = *(const float4*)&W[(size_t)(n0 + row) * 512 + kk + lk4 * 4];
            Bs[lk4 * 4 + 0][row] = vb.x;
            Bs[lk4 * 4 + 1][row] = vb.y;
            Bs[lk4 * 4 + 2][row] = vb.z;
            Bs[lk4 * 4 + 3][row] = vb.w;
        }
        __syncthreads();
#pragma unroll
        for (int k = 0; k < 16; ++k) {
            float4 a0 = *(const float4*)&As[k][tm * 8];
            float4 a1 = *(const float4*)&As[k][tm * 8 + 4];
            float4 b0 = *(const float4*)&Bs[k][tn * 4];
            float4 b1 = *(const float4*)&Bs[k][64 + tn * 4];
            float ar[8] = {a0.x, a0.y, a0.z, a0.w, a1.x, a1.y, a1.z, a1.w};
            float bc[8] = {b0.x, b0.y, b0.z, b0.w, b1.x, b1.y, b1.z, b1.w};
#pragma unroll
            for (int i = 0; i < 8; ++i)
#pragma unroll
                for (int j = 0; j < 8; ++j)
                    acc[i][j] = fmaf(ar[i], bc[j], acc[i][j]);
        }
        __syncthreads();
    }

    float4 bv0 = *(const float4*)&bias[n0 + tn * 4];
    float4 bv1 = *(const float4*)&bias[n0 + 64 + tn * 4];
    const float bb[8] = {bv0.x, bv0.y, bv0.z, bv0.w, bv1.x, bv1.y, bv1.z, bv1.w};
#pragma unroll
    for (int i = 0; i < 8; ++i) {
        const size_t rowoff = (size_t)(m0 + tm * 8 + i) * 512 + n0;
        float4 o0, o1;
        o0.x = acc[i][0] + bb[0]; o0.y = acc[i][1] + bb[1];
        o0.z = acc[i][2] + bb[2]; o0.w = acc[i][3] + bb[3];
        o1.x = acc[i][4] + bb[4]; o1.y = acc[i][5] + bb[5];
        o1.z = acc[i][6] + bb[6]; o1.w = acc[i][7] + bb[7];
        *(float4*)&C[rowoff + tn * 4] = o0;
        *(float4*)&C[rowoff + 64 + tn * 4] = o1;
    }
}

// fast tanh: 1 - 2/(exp2(2*log2e*x)+1); exact at +/-inf, ~1e-6 abs error
__device__ __forceinline__ float fast_tanh(float x)
{
    const float e = __builtin_amdgcn_exp2f(x * 2.88539008177793f);
    return fmaf(-2.0f, __builtin_amdgcn_rcpf(e + 1.0f), 1.0f);
}

// ---------------------------------------------------------------------------
// Recurrent scan = round-9 structure with ONE change: the 16 W ds_read_b128
// per thread are HOISTED to the top of the loop body, BEFORE the poll spin,
// pinned with sched_barrier(0). W's LDS region is written once at init, so
// these reads are barrier-independent; issuing them first lets the LDS W
// stream (~0.6 us) complete UNDER the sync round-trip instead of after the
// barrier (round 9 paid it serially post-barrier). Post-barrier work is now
// only h-broadcast reads + FMA on preloaded regs + reduce + publish.
//
// Geometry: 256 WGs x 512 thr, 1 WG/CU (136 KB LDS). Group g (32) = batch
// pair (2g,2g+1); 8 slice-WGs (bid = g + 32s, same XCD); slice owns rows
// [64s,64s+64); W slice in LDS wave-block layout (conflict-free).
// Sync: tagged-u64 relaxed agent atomics, s_sleep poll, parity double-buffer,
// own rows self-routed via LDS, ONE barrier/step (proof rounds 2-9).
// ---------------------------------------------------------------------------
#define WLD(i)  const float4 w##i = wb[(i) * 64]
#define WFMA(i, accA, accB) do { \
    const float4 hp = h0[i]; const float4 hq = h1[i]; \
    accA = fmaf(w##i.x, hp.x, accA); accA = fmaf(w##i.y, hp.y, accA); \
    accA = fmaf(w##i.z, hp.z, accA); accA = fmaf(w##i.w, hp.w, accA); \
    accB = fmaf(w##i.x, hq.x, accB); accB = fmaf(w##i.y, hq.y, accB); \
    accB = fmaf(w##i.z, hq.z, accB); accB = fmaf(w##i.w, hq.w, accB); } while (0)

__global__ __launch_bounds__(512, 2)
void rnn_scan(const float* __restrict__ proj, const float* __restrict__ Whh,
              const float* __restrict__ bhh, float* __restrict__ out,
              float* __restrict__ hidden, unsigned long long* __restrict__ hbuf)
{
    extern __shared__ float lds[];
    float4* Wv4 = (float4*)lds;              // 8192 float4 = 128 KB
    float4* hS4 = (float4*)(lds + 32768);    // [p][b][136] float4 (17-pad)
    float*  hSf = lds + 32768;               // scalar view, 2176 floats

    const int t    = threadIdx.x;
    const int bid  = blockIdx.x;
    const int g    = bid & 31;               // group = batch pair
    const int s    = bid >> 5;               // slice 0..7 (same XCD)
    const int b0   = g * 2;
    const int base = s * 64;
    const int w    = t >> 6;                 // wave 0..7
    const int l    = t & 63;
    const int rr   = l & 7;                  // row-in-wave
    const int kc   = l >> 3;                 // k-chunk 0..7 (64 k each)
    const int row  = base + w * 8 + rr;      // output row (64 per WG)

    // ---- one-time: W slice -> LDS in per-wave-block layout ----
    const float4* Wg4 = (const float4*)Whh;
    {
        const int k0 = kc * 16;
#pragma unroll
        for (int j = 0; j < 16; ++j)
            Wv4[w * 1024 + j * 64 + l] = Wg4[(size_t)row * 128 + k0 + j];
    }
    const bool pub  = (kc < 2);
    const float breg = pub ? bhh[row] : 0.f;

    // init both h parities to 0 (= h_init; also covers step-0 self-route)
    for (int i = t; i < 2176; i += 512) hSf[i] = 0.f;
    __syncthreads();

    const bool own  = (t >= base) && (t < base + 64);   // hid t self-routed
    const int  pado = (t >> 6) * 68 + (t & 63);         // padded scalar offset

    // proj pipeline: value for step 0 (publisher kc selects batch b0+kc)
    float pv_next = 0.f;
    if (pub) pv_next = proj[(size_t)(b0 + kc) * HID + row];

    unsigned long long* gb = hbuf + (size_t)g * 4096;   // [p][b][512] u64
    const float4* wb = Wv4 + w * 1024 + l;

    for (int step = 0; step < SEQ; ++step) {
        const int p = step & 1;

        const float pv = pv_next;
        if (pub && step + 1 < SEQ)
            pv_next = proj[((size_t)(step + 1) * BATCH + (b0 + kc)) * HID + row];

        // ---- HOISTED W reads: issue before the poll so the LDS stream
        //      completes under the sync round-trip (W is step-invariant).
        WLD(0);  WLD(1);  WLD(2);  WLD(3);
        WLD(4);  WLD(5);  WLD(6);  WLD(7);
        WLD(8);  WLD(9);  WLD(10); WLD(11);
        WLD(12); WLD(13); WLD(14); WLD(15);
        __builtin_amdgcn_sched_barrier(0);   // pin: nothing crosses

        // ---- poll 2 tagged u64 (hid t, batch 0/1), stage into hS[p] ----
        if (!own) {
            const unsigned int want = (unsigned int)step;
            const unsigned long long* f0 = gb + (size_t)p * 2048 + t;
            const unsigned long long* f1 = f0 + 512;
            unsigned long long x0 = 0, x1 = 0;
            bool ok0 = false, ok1 = false;
            int spins = 0;
            for (;;) {
                if (!ok0) {
                    x0 = __hip_atomic_load(f0, __ATOMIC_RELAXED, __HIP_MEMORY_SCOPE_AGENT);
                    ok0 = (unsigned int)(x0 >> 32) == want;
                }
                if (!ok1) {
                    x1 = __hip_atomic_load(f1, __ATOMIC_RELAXED, __HIP_MEMORY_SCOPE_AGENT);
                    ok1 = (unsigned int)(x1 >> 32) == want;
                }
                if (ok0 & ok1) break;
                __builtin_amdgcn_s_sleep(1);
                if (++spins > 4096) {              // hang-proofing only
                    __builtin_amdgcn_fence(__ATOMIC_ACQUIRE, "agent");
                    spins = 0;
                }
            }
            hSf[p * 1088 + pado]       = __uint_as_float((unsigned int)x0);
            hSf[p * 1088 + 544 + pado] = __uint_as_float((unsigned int)x1);
        }
        __syncthreads();   // the ONLY barrier per step

        // ---- matvec: preloaded W regs x broadcast h (padded) ----
        const float4* h0 = hS4 + p * 272 + kc * 17;
        const float4* h1 = h0 + 136;
        float a0e = 0.f, a0o = 0.f, a1e = 0.f, a1o = 0.f;
        WFMA(0,  a0e, a1e); WFMA(1,  a0o, a1o);
        WFMA(2,  a0e, a1e); WFMA(3,  a0o, a1o);
        WFMA(4,  a0e, a1e); WFMA(5,  a0o, a1o);
        WFMA(6,  a0e, a1e); WFMA(7,  a0o, a1o);
        WFMA(8,  a0e, a1e); WFMA(9,  a0o, a1o);
        WFMA(10, a0e, a1e); WFMA(11, a0o, a1o);
        WFMA(12, a0e, a1e); WFMA(13, a0o, a1o);
        WFMA(14, a0e, a1e); WFMA(15, a0o, a1o);
        float s0 = a0e + a0o;
        float s1 = a1e + a1o;
        // butterfly over the kc bits (l^8, l^16, l^32): all lanes get totals
        s0 += __shfl_xor(s0, 8, 64);  s1 += __shfl_xor(s1, 8, 64);
        s0 += __shfl_xor(s0, 16, 64); s1 += __shfl_xor(s1, 16, 64);
        s0 += __shfl_xor(s0, 32, 64); s1 += __shfl_xor(s1, 32, 64);

        // ---- tanh + publish (kc==0 -> batch b0, kc==1 -> b0+1) ----
        if (pub) {
            const float sum = (kc == 0) ? s0 : s1;
            const int   bb  = b0 + kc;
            const float hn  = fast_tanh(pv + breg + sum);
            out[((size_t)step * BATCH + bb) * HID + row] = hn;
            const unsigned long long pk =
                ((unsigned long long)(unsigned int)(step + 1) << 32) |
                (unsigned long long)__float_as_uint(hn);
            __hip_atomic_store(gb + (size_t)(p ^ 1) * 2048 + (size_t)kc * 512 + row,
                               pk, __ATOMIC_RELAXED, __HIP_MEMORY_SCOPE_AGENT);
            hSf[(p ^ 1) * 1088 + kc * 544 + (row >> 6) * 68 + (row & 63)] = hn;
            if (step == SEQ - 1) hidden[(size_t)bb * HID + row] = hn;
        }
        // no trailing barrier: next step's pre-barrier LDS writes touch only
        // parity p^1 (disjoint from this step's hS[p] reads); hS[p] can only
        // be overwritten after the NEXT barrier, which gates on all threads
        // finishing this step's reads.
    }
}

// ---------------------------------------------------------------------------
extern "C" void kernel_launch(void* const* d_in, const int* in_sizes, int n_in,
                              void* d_out, int out_size, void* d_ws, size_t ws_size,
                              hipStream_t stream)
{
    (void)in_sizes; (void)n_in; (void)out_size; (void)ws_size;

    const float* x    = (const float*)d_in[0];
    const float* Wih0 = (const float*)d_in[1];
    const float* Whh0 = (const float*)d_in[2];
    const float* bih0 = (const float*)d_in[3];
    const float* bhh0 = (const float*)d_in[4];
    const float* Wih1 = (const float*)d_in[5];
    const float* Whh1 = (const float*)d_in[6];
    const float* bih1 = (const float*)d_in[7];
    const float* bhh1 = (const float*)d_in[8];

    float* out1   = (float*)d_out;                        // [S][B][H]
    float* hidden = out1 + (size_t)SEQ * BATCH * HID;     // [2][B][H]

    float* proj = (float*)d_ws;                           // [S][B][H] f32
    // per-layer tagged h buffers: [32 groups][2 parity][2 batch][512] u64
    unsigned long long* hbufA = (unsigned long long*)(proj + (size_t)SEQ * BATCH * HID);
    unsigned long long* hbufB = hbufA + (size_t)32 * 4096;

    // zero both layers' tag arrays (tag 0 == epoch 0, h = 0)
    hipMemsetAsync(hbufA, 0, (size_t)2 * 32 * 4096 * sizeof(unsigned long long),
                   stream);

    const size_t shmem = (size_t)(32768 + 2176) * sizeof(float);  // 139776 B
    (void)hipFuncSetAttribute((const void*)rnn_scan,
                              hipFuncAttributeMaxDynamicSharedMemorySize, (int)shmem);

    // ---- layer 0 ----
    proj_gemm<<<dim3(4096), dim3(256), 0, stream>>>(x, Wih0, bih0, proj);
    {
        const float* p = proj; const float* w = Whh0; const float* bb = bhh0;
        float* o = out1; float* hd = hidden; unsigned long long* hb = hbufA;
        void* args[] = {&p, &w, &bb, &o, &hd, &hb};
        hipLaunchCooperativeKernel((const void*)rnn_scan, dim3(256), dim3(512),
                                   args, (unsigned)shmem, stream);
    }

    // ---- layer 1 (out0 staged in d_out's out1 region) ----
    proj_gemm<<<dim3(4096), dim3(256), 0, stream>>>(out1, Wih1, bih1, proj);
    {
        const float* p = proj; const float* w = Whh1; const float* bb = bhh1;
        float* o = out1; float* hd = hidden + BATCH * HID; unsigned long long* hb = hbufB;
        void* args[] = {&p, &w, &bb, &o, &hd, &hb};
        hipLaunchCooperativeKernel((const void*)rnn_scan, dim3(256), dim3(512),
                                   args, (unsigned)shmem, stream);
    }
}